// Round 7
// baseline (753.881 us; speedup 1.0000x reference)
//
#include <hip/hip_runtime.h>
#include <hip/hip_fp16.h>

// GCN: out = Ahat*(relu(Ahat*(x@W1)+b1))@W2 + b2,  Ahat = D^-1/2 (A+I) D^-1/2
// N=100000, E=1600000, IN=256, HID=128, OUT=64, fp32 in/out.
// R13: replace the 4-kernel bucket build (hist/scan/scatter/csr) with a
//   direct CSR build -- R12 showed bucket_scatter alone was 83us (top
//   dispatch, 29% occ, 550K serialized bcur atomics, 470K LDS conflicts):
//     1) prep: W transposes + deg[] via global atomicAdd (pipelined, no
//        per-block structure to serialize on)
//     2) node_scan: 1-block exclusive scan of deg -> off/cur/dinv
//     3) csr_scatter: r = atomicAdd(&cur[dst]); csr[r] = src
//   agg/gemm stages unchanged from R12 (R6 agg structure + dinv fold):
//   agg rows pre-scaled by dinv (gemm1 epilogue; z16 carries the fold).

#define IN_DIM 256
#define HID_DIM 128
#define OUT_DIM 64

typedef _Float16 half8 __attribute__((ext_vector_type(8)));
typedef float floatx4 __attribute__((ext_vector_type(4)));

// ---- build 1: weight transposes (fp16) + degree histogram ----
__global__ __launch_bounds__(256) void prep_kernel(const int* __restrict__ dst, int E,
                                                   int* __restrict__ deg,
                                                   const float* __restrict__ W1,
                                                   const float* __restrict__ W2,
                                                   __half* __restrict__ Wt1,
                                                   __half* __restrict__ Wt2) {
  int gid = blockIdx.x * 256 + threadIdx.x, gsz = gridDim.x * 256;
  for (int i = gid; i < IN_DIM * HID_DIM; i += gsz) {
    int n = i / IN_DIM, k = i % IN_DIM;
    Wt1[i] = __float2half(W1[k * HID_DIM + n]);
  }
  for (int i = gid; i < HID_DIM * OUT_DIM; i += gsz) {
    int n = i / HID_DIM, k = i % HID_DIM;
    Wt2[i] = __float2half(W2[k * OUT_DIM + n]);
  }
  for (int i = gid; i < E; i += gsz) atomicAdd(&deg[dst[i]], 1);
}

// ---- build 2: exclusive scan over N nodes -> off/cur; dinv = rsqrt(deg+1) ----
__global__ __launch_bounds__(1024) void node_scan(const int* __restrict__ deg, int N,
                                                  int E, int* __restrict__ off,
                                                  int* __restrict__ cur,
                                                  float* __restrict__ dinv) {
  __shared__ int sh[1024];
  int t = threadIdx.x;
  int L = (N + 1023) / 1024;
  int i0 = t * L, i1 = min(N, i0 + L);
  int s = 0;
  for (int i = i0; i < i1; i++) s += deg[i];
  sh[t] = s;
  __syncthreads();
  for (int st = 1; st < 1024; st <<= 1) {
    int a = (t >= st) ? sh[t - st] : 0;
    __syncthreads();
    sh[t] += a;
    __syncthreads();
  }
  int base = sh[t] - s;  // exclusive prefix of this thread's range
  for (int i = i0; i < i1; i++) {
    int d = deg[i];
    off[i] = base;
    cur[i] = base;
    dinv[i] = 1.0f / sqrtf((float)(d + 1));
    base += d;
  }
  if (t == 0) off[N] = E;
}

// ---- build 3: direct CSR scatter (atomic-with-return per edge) ----
__global__ __launch_bounds__(256) void csr_scatter(const int* __restrict__ src,
                                                   const int* __restrict__ dst, int E,
                                                   int* __restrict__ cur,
                                                   int* __restrict__ csr) {
  int gid = blockIdx.x * 256 + threadIdx.x, gsz = gridDim.x * 256;
  for (int i = gid; i < E; i += gsz) {
    int r = atomicAdd(&cur[dst[i]], 1);
    csr[r] = src[i];
  }
}

// C[M x NC](fp16) = A[M x K] @ W[K x NC] via v_mfma_f32_16x16x32_f16.
// SCALE: multiply output row by rowscale[row] (dinv fold for layer 1).
template <int K, int NC, typename AT, bool SCALE>
__global__ __launch_bounds__(256) void mfma_gemm(const AT* __restrict__ A,
                                                 const __half* __restrict__ Wt,
                                                 __half* __restrict__ C, int M,
                                                 const float* __restrict__ rowscale) {
  constexpr int BK = 32;
  constexpr int STR = BK + 8;  // padded LDS row stride (halves) -> 2-way max
  constexpr int CT = NC / 16;
  __shared__ _Float16 As[128 * STR];
  __shared__ _Float16 Ws[NC * STR];
  int row0 = blockIdx.x * 128;
  int t = threadIdx.x;
  int wave = t >> 6, lane = t & 63, quad = lane >> 4, lr = lane & 15;
  floatx4 acc[2][CT] = {};
  int arow = t >> 1, ako = (t & 1) * 16;
  int grow = row0 + arow;

  for (int k0 = 0; k0 < K; k0 += BK) {
    {
      half8 h0 = {}, h1 = {};
      if (grow < M) {
        if constexpr (sizeof(AT) == 4) {
          const float4* ap = (const float4*)(A + (size_t)grow * K + k0 + ako);
          float4 v0 = ap[0], v1 = ap[1], v2 = ap[2], v3 = ap[3];
          h0[0] = (_Float16)v0.x; h0[1] = (_Float16)v0.y;
          h0[2] = (_Float16)v0.z; h0[3] = (_Float16)v0.w;
          h0[4] = (_Float16)v1.x; h0[5] = (_Float16)v1.y;
          h0[6] = (_Float16)v1.z; h0[7] = (_Float16)v1.w;
          h1[0] = (_Float16)v2.x; h1[1] = (_Float16)v2.y;
          h1[2] = (_Float16)v2.z; h1[3] = (_Float16)v2.w;
          h1[4] = (_Float16)v3.x; h1[5] = (_Float16)v3.y;
          h1[6] = (_Float16)v3.z; h1[7] = (_Float16)v3.w;
        } else {
          const half8* ap = (const half8*)(A + (size_t)grow * K + k0 + ako);
          h0 = ap[0];
          h1 = ap[1];
        }
      }
      *(half8*)&As[arow * STR + ako] = h0;
      *(half8*)&As[arow * STR + ako + 8] = h1;
    }
    if constexpr (NC == 128) {
      int r = t >> 1, ko = (t & 1) * 16;
      const half8* wp = (const half8*)(Wt + (size_t)r * K + k0 + ko);
      *(half8*)&Ws[r * STR + ko] = wp[0];
      *(half8*)&Ws[r * STR + ko + 8] = wp[1];
    } else {  // NC == 64
      int r = t >> 2, ko = (t & 3) * 8;
      *(half8*)&Ws[r * STR + ko] = *(const half8*)(Wt + (size_t)r * K + k0 + ko);
    }
    __syncthreads();
    {
      int a_off = (wave * 32 + lr) * STR + quad * 8;
      half8 a0 = *(const half8*)&As[a_off];
      half8 a1 = *(const half8*)&As[a_off + 16 * STR];
      int b_off = lr * STR + quad * 8;
#pragma unroll
      for (int ct = 0; ct < CT; ct++) {
        half8 bfr = *(const half8*)&Ws[b_off + ct * 16 * STR];
        acc[0][ct] = __builtin_amdgcn_mfma_f32_16x16x32_f16(a0, bfr, acc[0][ct], 0, 0, 0);
        acc[1][ct] = __builtin_amdgcn_mfma_f32_16x16x32_f16(a1, bfr, acc[1][ct], 0, 0, 0);
      }
    }
    __syncthreads();
  }
#pragma unroll
  for (int rt = 0; rt < 2; rt++) {
    int rbase = row0 + wave * 32 + rt * 16 + quad * 4;
#pragma unroll
    for (int i = 0; i < 4; i++) {
      int row = rbase + i;
      if (row < M) {
        float sc = 1.f;
        if constexpr (SCALE) sc = rowscale[row];
#pragma unroll
        for (int ct = 0; ct < CT; ct++) {
          int col = ct * 16 + lr;
          C[(size_t)row * NC + col] = __float2half(acc[rt][ct][i] * sc);
        }
      }
    }
  }
}

// agg layer 1: one wave per node, NC=128, lane covers 2 cols (__half2). x8
// unroll. h rows pre-scaled by dinv (gemm1 epilogue) -> NO per-edge dinv
// loads. Output stores di*relu(...) so layer 2 inherits the row scale.
__global__ __launch_bounds__(256) void agg1_kernel(const __half* __restrict__ h,
                                                   const int* __restrict__ off,
                                                   const int* __restrict__ csr,
                                                   const float* __restrict__ dinv,
                                                   const float* __restrict__ bias,
                                                   __half* __restrict__ out, int N) {
  constexpr int NC = HID_DIM;
  int node = blockIdx.x * 4 + (threadIdx.x >> 6);
  int lane = threadIdx.x & 63;
  if (node >= N) return;
  int c = lane * 2;
  float a0 = 0.f, a1 = 0.f;
  auto gather = [&](int sidx) {
    __half2 hv = *(const __half2*)(h + (size_t)sidx * NC + c);
    float2 f = __half22float2(hv);
    a0 += f.x;
    a1 += f.y;
  };
  gather(node);  // self-loop (row already carries dinv[node])
  int e0 = off[node], e1 = off[node + 1];
  int e = e0;
  for (; e + 8 <= e1; e += 8) {
    int s0 = csr[e], s1 = csr[e + 1], s2 = csr[e + 2], s3 = csr[e + 3];
    int s4 = csr[e + 4], s5 = csr[e + 5], s6 = csr[e + 6], s7 = csr[e + 7];
    gather(s0); gather(s1); gather(s2); gather(s3);
    gather(s4); gather(s5); gather(s6); gather(s7);
  }
  for (; e + 4 <= e1; e += 4) {
    int s0 = csr[e], s1 = csr[e + 1], s2 = csr[e + 2], s3 = csr[e + 3];
    gather(s0); gather(s1); gather(s2); gather(s3);
  }
  for (; e < e1; e++) gather(csr[e]);
  float di = dinv[node];
  float r0 = fmaxf(di * a0 + bias[c], 0.f) * di;      // trailing *di = L2 fold
  float r1 = fmaxf(di * a1 + bias[c + 1], 0.f) * di;
  *(__half2*)(out + (size_t)node * NC + c) = __floats2half2_rn(r0, r1);
}

// agg layer 2: NC=64 -> half-wave per node (32 lanes x __half2). x4 unroll.
// Rows pre-scaled via z16 fold -> no per-edge dinv loads.
__global__ __launch_bounds__(256) void agg2_kernel(const __half* __restrict__ h,
                                                   const int* __restrict__ off,
                                                   const int* __restrict__ csr,
                                                   const float* __restrict__ dinv,
                                                   const float* __restrict__ bias,
                                                   float* __restrict__ out, int N) {
  constexpr int NC = OUT_DIM;
  int node = blockIdx.x * 8 + (threadIdx.x >> 5);
  int hl = threadIdx.x & 31;
  if (node >= N) return;
  int c = hl * 2;
  float a0 = 0.f, a1 = 0.f;
  auto gather = [&](int sidx) {
    __half2 hv = *(const __half2*)(h + (size_t)sidx * NC + c);
    float2 f = __half22float2(hv);
    a0 += f.x;
    a1 += f.y;
  };
  gather(node);
  int e0 = off[node], e1 = off[node + 1];
  int e = e0;
  for (; e + 4 <= e1; e += 4) {
    int s0 = csr[e], s1 = csr[e + 1], s2 = csr[e + 2], s3 = csr[e + 3];
    gather(s0); gather(s1); gather(s2); gather(s3);
  }
  for (; e < e1; e++) gather(csr[e]);
  float di = dinv[node];
  out[(size_t)node * NC + c] = di * a0 + bias[c];
  out[(size_t)node * NC + c + 1] = di * a1 + bias[c + 1];
}

extern "C" void kernel_launch(void* const* d_in, const int* in_sizes, int n_in,
                              void* d_out, int out_size, void* d_ws, size_t ws_size,
                              hipStream_t stream) {
  const float* x  = (const float*)d_in[0];
  const int*   ei = (const int*)d_in[1];
  const float* W1 = (const float*)d_in[2];
  const float* b1 = (const float*)d_in[3];
  const float* W2 = (const float*)d_in[4];
  const float* b2 = (const float*)d_in[5];
  float* out = (float*)d_out;

  int N = in_sizes[0] / IN_DIM;
  int E = in_sizes[1] / 2;
  const int* src = ei;
  const int* dst = ei + E;

  char* p = (char*)d_ws;
  auto alloc = [&](size_t bytes) {
    char* q = p;
    p += (bytes + 255) & ~(size_t)255;
    return q;
  };
  int*    deg   = (int*)alloc((size_t)N * 4);
  int*    off   = (int*)alloc((size_t)(N + 1) * 4);
  int*    cur   = (int*)alloc((size_t)N * 4);
  int*    csr   = (int*)alloc((size_t)E * 4);
  float*  dinv  = (float*)alloc((size_t)N * 4);
  __half* h1    = (__half*)alloc((size_t)N * HID_DIM * 2);  // reused as h2
  __half* z16   = (__half*)alloc((size_t)N * HID_DIM * 2);
  __half* Wt1   = (__half*)alloc((size_t)IN_DIM * HID_DIM * 2);
  __half* Wt2   = (__half*)alloc((size_t)HID_DIM * OUT_DIM * 2);
  __half* h2    = h1;
  (void)ws_size; (void)n_in; (void)out_size;

  hipMemsetAsync(deg, 0, (size_t)N * 4, stream);

  // direct CSR build: deg -> scan -> scatter
  prep_kernel<<<1024, 256, 0, stream>>>(dst, E, deg, W1, W2, Wt1, Wt2);
  node_scan<<<1, 1024, 0, stream>>>(deg, N, E, off, cur, dinv);
  csr_scatter<<<2048, 256, 0, stream>>>(src, dst, E, cur, csr);

  int gb = (N + 127) / 128;
  // layer 1: h1 rows pre-scaled by dinv (SCALE=true)
  mfma_gemm<IN_DIM, HID_DIM, float, true><<<gb, 256, 0, stream>>>(x, Wt1, h1, N, dinv);
  agg1_kernel<<<(N + 3) / 4, 256, 0, stream>>>(h1, off, csr, dinv, b1, z16, N);

  // layer 2: z16 already carries the dinv row-scale
  mfma_gemm<HID_DIM, OUT_DIM, __half, false><<<gb, 256, 0, stream>>>(z16, Wt2, h2, N, nullptr);
  agg2_kernel<<<(N + 7) / 8, 256, 0, stream>>>(h2, off, csr, dinv, b2, out, N);
}

// Round 9
// 407.991 us; speedup vs baseline: 1.8478x; 1.8478x over previous
//
#include <hip/hip_runtime.h>
#include <hip/hip_fp16.h>

// GCN: out = Ahat*(relu(Ahat*(x@W1)+b1))@W2 + b2,  Ahat = D^-1/2 (A+I) D^-1/2
// N=100000, E=1600000, IN=256, HID=128, OUT=64, fp32 in/out.
// R15 = R14 resubmit (round-8 bench died on container acquisition; third
//   infra flake this session -- identical-source resubmits passed in R4/R6).
// R14: surgical revert. Ledger: R6=402 (scatter cfg 8192/256blk, <=68us);
//   R12=425 = R6 + dinv-fold(win: agg1 left top-5) + STAGE_CAP 2048(REGRESSION:
//   scatter 83us, 550K serialized bcur atomics); R13 direct-CSR build = 754
//   (node_scan 281us serial-uncoalesced; per-edge atomic-return scatter slow).
//   This round: R12 source with bucket_scatter back to STAGE_CAP=8192,
//   grid=max(256, E/8192) -- the exact R6 scatter. Nothing else changed.

#define IN_DIM 256
#define HID_DIM 128
#define OUT_DIM 64
#define BSHIFT 7
#define MAXNB 1024      // supports N <= 131072
#define STAGE_CAP 8192  // max edges staged per scatter block (32 KB LDS)

typedef _Float16 half8 __attribute__((ext_vector_type(8)));
typedef float floatx4 __attribute__((ext_vector_type(4)));

// ---- build A: bucket histogram (LDS-privatized) + W^T fp16 conversion ----
__global__ __launch_bounds__(256) void bucket_hist(const int* __restrict__ dst, int E,
                                                   int NB, int* __restrict__ bcnt,
                                                   const float* __restrict__ W1,
                                                   const float* __restrict__ W2,
                                                   __half* __restrict__ Wt1,
                                                   __half* __restrict__ Wt2) {
  __shared__ int h[MAXNB];
  int t = threadIdx.x;
  int gid = blockIdx.x * 256 + t, gsz = gridDim.x * 256;
  // fold in the (tiny) weight transposes
  for (int i = gid; i < IN_DIM * HID_DIM; i += gsz) {
    int n = i / IN_DIM, k = i % IN_DIM;
    Wt1[i] = __float2half(W1[k * HID_DIM + n]);
  }
  for (int i = gid; i < HID_DIM * OUT_DIM; i += gsz) {
    int n = i / HID_DIM, k = i % HID_DIM;
    Wt2[i] = __float2half(W2[k * OUT_DIM + n]);
  }
  for (int i = t; i < MAXNB; i += 256) h[i] = 0;
  __syncthreads();
  for (int i = gid; i < E; i += gsz) atomicAdd(&h[dst[i] >> BSHIFT], 1);
  __syncthreads();
  for (int i = t; i < NB; i += 256) {
    int v = h[i];
    if (v) atomicAdd(&bcnt[i], v);
  }
}

// ---- build B: scan bucket counts; init global cursors; off[N]=E ----
__global__ __launch_bounds__(1024) void bucket_scan(const int* __restrict__ bcnt, int NB,
                                                    int E, int* __restrict__ boff,
                                                    int* __restrict__ bcur,
                                                    int* __restrict__ off, int N) {
  __shared__ int sh[1024];
  int t = threadIdx.x;
  int v = (t < NB) ? bcnt[t] : 0;
  sh[t] = v;
  __syncthreads();
  for (int s = 1; s < 1024; s <<= 1) {
    int a = (t >= s) ? sh[t - s] : 0;
    __syncthreads();
    sh[t] += a;
    __syncthreads();
  }
  if (t < NB) {
    int ex = sh[t] - v;
    boff[t] = ex;
    bcur[t] = ex;
  }
  if (t == 0) {
    boff[NB] = E;
    off[N] = E;
  }
}

// ---- build C: LDS-staged counting sort of each chunk, coalesced writeout ----
// pairs[g] = (src<<7)|(dst&127), bucket-contiguous.
__global__ __launch_bounds__(256) void bucket_scatter(const int* __restrict__ src,
                                                      const int* __restrict__ dst, int E,
                                                      int NB, int* __restrict__ bcur,
                                                      int* __restrict__ pairs) {
  __shared__ int hist[MAXNB];
  __shared__ int base_l[MAXNB + 1];  // exclusive scan of hist (LDS slot base)
  __shared__ int base_g[MAXNB];     // this block's run base in global pairs[]
  __shared__ int cur[MAXNB];
  __shared__ int sm[256];
  __shared__ int stage[STAGE_CAP];
  int t = threadIdx.x;
  int chunk = (E + gridDim.x - 1) / gridDim.x;
  int s0 = blockIdx.x * chunk, s1 = min(E, s0 + chunk);
  int cnt = s1 - s0;  // <= STAGE_CAP by launch config

  for (int i = t; i < MAXNB; i += 256) hist[i] = 0;
  __syncthreads();
  for (int i = s0 + t; i < s1; i += 256) atomicAdd(&hist[dst[i] >> BSHIFT], 1);
  __syncthreads();
  // scan 1024 hist entries with 256 threads (4 each)
  {
    int i0 = t * 4;
    int v0 = hist[i0], v1 = hist[i0 + 1], v2 = hist[i0 + 2], v3 = hist[i0 + 3];
    int s = v0 + v1 + v2 + v3;
    sm[t] = s;
    __syncthreads();
    for (int st = 1; st < 256; st <<= 1) {
      int a = (t >= st) ? sm[t - st] : 0;
      __syncthreads();
      sm[t] += a;
      __syncthreads();
    }
    int ex = sm[t] - s;
    base_l[i0] = ex;
    base_l[i0 + 1] = ex + v0;
    base_l[i0 + 2] = ex + v0 + v1;
    base_l[i0 + 3] = ex + v0 + v1 + v2;
    cur[i0] = ex;
    cur[i0 + 1] = ex + v0;
    cur[i0 + 2] = ex + v0 + v1;
    cur[i0 + 3] = ex + v0 + v1 + v2;
    if (v0) base_g[i0] = atomicAdd(&bcur[i0], v0);
    if (v1) base_g[i0 + 1] = atomicAdd(&bcur[i0 + 1], v1);
    if (v2) base_g[i0 + 2] = atomicAdd(&bcur[i0 + 2], v2);
    if (v3) base_g[i0 + 3] = atomicAdd(&bcur[i0 + 3], v3);
    if (t == 0) base_l[MAXNB] = cnt;
  }
  __syncthreads();
  // rank-scatter into LDS stage (packed payload)
  for (int i = s0 + t; i < s1; i += 256) {
    int d = dst[i];
    int bk = d >> BSHIFT;
    int r = atomicAdd(&cur[bk], 1);
    stage[r] = (src[i] << BSHIFT) | (d & ((1 << BSHIFT) - 1));
  }
  __syncthreads();
  // coalesced writeout: slot j -> bucket via binary search on base_l
  for (int j = t; j < cnt; j += 256) {
    int lo = 0, hi = MAXNB;
    while (hi - lo > 1) {
      int mid = (lo + hi) >> 1;
      if (base_l[mid] <= j) lo = mid;
      else hi = mid;
    }
    pairs[base_g[lo] + (j - base_l[lo])] = stage[j];
  }
}

// ---- build D: per-bucket counting sort -> csr/off/dinv ----
__global__ __launch_bounds__(256) void bucket_csr(const int* __restrict__ pairs,
                                                  const int* __restrict__ boff, int N,
                                                  int* __restrict__ csr,
                                                  int* __restrict__ off,
                                                  float* __restrict__ dinv) {
  int b = blockIdx.x;
  int t = threadIdx.x;
  int n0 = b << BSHIFT;
  int cnt = min(128, N - n0);
  __shared__ int ldeg[128], sh[128], lcur[128];
  if (t < 128) ldeg[t] = 0;
  __syncthreads();
  int e0 = boff[b], e1 = boff[b + 1];
  for (int e = e0 + t; e < e1; e += 256) atomicAdd(&ldeg[pairs[e] & 127], 1);
  __syncthreads();
  int v = (t < 128) ? ldeg[t] : 0;
  if (t < 128) sh[t] = v;
  __syncthreads();
  for (int s = 1; s < 128; s <<= 1) {
    int a = (t < 128 && t >= s) ? sh[t - s] : 0;
    __syncthreads();
    if (t < 128) sh[t] += a;
    __syncthreads();
  }
  if (t < cnt) {
    int ex = sh[t] - v;
    off[n0 + t] = e0 + ex;
    dinv[n0 + t] = 1.0f / sqrtf((float)(v + 1));
    lcur[t] = ex;
  }
  __syncthreads();
  for (int e = e0 + t; e < e1; e += 256) {
    int pk = pairs[e];
    int r = atomicAdd(&lcur[pk & 127], 1);
    csr[e0 + r] = pk >> BSHIFT;
  }
}

// C[M x NC](fp16) = A[M x K] @ W[K x NC] via v_mfma_f32_16x16x32_f16.
// SCALE: multiply output row by rowscale[row] (dinv fold for layer 1).
template <int K, int NC, typename AT, bool SCALE>
__global__ __launch_bounds__(256) void mfma_gemm(const AT* __restrict__ A,
                                                 const __half* __restrict__ Wt,
                                                 __half* __restrict__ C, int M,
                                                 const float* __restrict__ rowscale) {
  constexpr int BK = 32;
  constexpr int STR = BK + 8;  // padded LDS row stride (halves) -> 2-way max
  constexpr int CT = NC / 16;
  __shared__ _Float16 As[128 * STR];
  __shared__ _Float16 Ws[NC * STR];
  int row0 = blockIdx.x * 128;
  int t = threadIdx.x;
  int wave = t >> 6, lane = t & 63, quad = lane >> 4, lr = lane & 15;
  floatx4 acc[2][CT] = {};
  int arow = t >> 1, ako = (t & 1) * 16;
  int grow = row0 + arow;

  for (int k0 = 0; k0 < K; k0 += BK) {
    {
      half8 h0 = {}, h1 = {};
      if (grow < M) {
        if constexpr (sizeof(AT) == 4) {
          const float4* ap = (const float4*)(A + (size_t)grow * K + k0 + ako);
          float4 v0 = ap[0], v1 = ap[1], v2 = ap[2], v3 = ap[3];
          h0[0] = (_Float16)v0.x; h0[1] = (_Float16)v0.y;
          h0[2] = (_Float16)v0.z; h0[3] = (_Float16)v0.w;
          h0[4] = (_Float16)v1.x; h0[5] = (_Float16)v1.y;
          h0[6] = (_Float16)v1.z; h0[7] = (_Float16)v1.w;
          h1[0] = (_Float16)v2.x; h1[1] = (_Float16)v2.y;
          h1[2] = (_Float16)v2.z; h1[3] = (_Float16)v2.w;
          h1[4] = (_Float16)v3.x; h1[5] = (_Float16)v3.y;
          h1[6] = (_Float16)v3.z; h1[7] = (_Float16)v3.w;
        } else {
          const half8* ap = (const half8*)(A + (size_t)grow * K + k0 + ako);
          h0 = ap[0];
          h1 = ap[1];
        }
      }
      *(half8*)&As[arow * STR + ako] = h0;
      *(half8*)&As[arow * STR + ako + 8] = h1;
    }
    if constexpr (NC == 128) {
      int r = t >> 1, ko = (t & 1) * 16;
      const half8* wp = (const half8*)(Wt + (size_t)r * K + k0 + ko);
      *(half8*)&Ws[r * STR + ko] = wp[0];
      *(half8*)&Ws[r * STR + ko + 8] = wp[1];
    } else {  // NC == 64
      int r = t >> 2, ko = (t & 3) * 8;
      *(half8*)&Ws[r * STR + ko] = *(const half8*)(Wt + (size_t)r * K + k0 + ko);
    }
    __syncthreads();
    {
      int a_off = (wave * 32 + lr) * STR + quad * 8;
      half8 a0 = *(const half8*)&As[a_off];
      half8 a1 = *(const half8*)&As[a_off + 16 * STR];
      int b_off = lr * STR + quad * 8;
#pragma unroll
      for (int ct = 0; ct < CT; ct++) {
        half8 bfr = *(const half8*)&Ws[b_off + ct * 16 * STR];
        acc[0][ct] = __builtin_amdgcn_mfma_f32_16x16x32_f16(a0, bfr, acc[0][ct], 0, 0, 0);
        acc[1][ct] = __builtin_amdgcn_mfma_f32_16x16x32_f16(a1, bfr, acc[1][ct], 0, 0, 0);
      }
    }
    __syncthreads();
  }
#pragma unroll
  for (int rt = 0; rt < 2; rt++) {
    int rbase = row0 + wave * 32 + rt * 16 + quad * 4;
#pragma unroll
    for (int i = 0; i < 4; i++) {
      int row = rbase + i;
      if (row < M) {
        float sc = 1.f;
        if constexpr (SCALE) sc = rowscale[row];
#pragma unroll
        for (int ct = 0; ct < CT; ct++) {
          int col = ct * 16 + lr;
          C[(size_t)row * NC + col] = __float2half(acc[rt][ct][i] * sc);
        }
      }
    }
  }
}

// agg layer 1: one wave per node, NC=128, lane covers 2 cols (__half2). x8
// unroll. h rows pre-scaled by dinv (gemm1 epilogue) -> NO per-edge dinv
// loads. Output stores di*relu(...) so layer 2 inherits the row scale.
__global__ __launch_bounds__(256) void agg1_kernel(const __half* __restrict__ h,
                                                   const int* __restrict__ off,
                                                   const int* __restrict__ csr,
                                                   const float* __restrict__ dinv,
                                                   const float* __restrict__ bias,
                                                   __half* __restrict__ out, int N) {
  constexpr int NC = HID_DIM;
  int node = blockIdx.x * 4 + (threadIdx.x >> 6);
  int lane = threadIdx.x & 63;
  if (node >= N) return;
  int c = lane * 2;
  float a0 = 0.f, a1 = 0.f;
  auto gather = [&](int sidx) {
    __half2 hv = *(const __half2*)(h + (size_t)sidx * NC + c);
    float2 f = __half22float2(hv);
    a0 += f.x;
    a1 += f.y;
  };
  gather(node);  // self-loop (row already carries dinv[node])
  int e0 = off[node], e1 = off[node + 1];
  int e = e0;
  for (; e + 8 <= e1; e += 8) {
    int s0 = csr[e], s1 = csr[e + 1], s2 = csr[e + 2], s3 = csr[e + 3];
    int s4 = csr[e + 4], s5 = csr[e + 5], s6 = csr[e + 6], s7 = csr[e + 7];
    gather(s0); gather(s1); gather(s2); gather(s3);
    gather(s4); gather(s5); gather(s6); gather(s7);
  }
  for (; e + 4 <= e1; e += 4) {
    int s0 = csr[e], s1 = csr[e + 1], s2 = csr[e + 2], s3 = csr[e + 3];
    gather(s0); gather(s1); gather(s2); gather(s3);
  }
  for (; e < e1; e++) gather(csr[e]);
  float di = dinv[node];
  float r0 = fmaxf(di * a0 + bias[c], 0.f) * di;      // trailing *di = L2 fold
  float r1 = fmaxf(di * a1 + bias[c + 1], 0.f) * di;
  *(__half2*)(out + (size_t)node * NC + c) = __floats2half2_rn(r0, r1);
}

// agg layer 2: NC=64 -> half-wave per node (32 lanes x __half2). x4 unroll.
// Rows pre-scaled via z16 fold -> no per-edge dinv loads.
__global__ __launch_bounds__(256) void agg2_kernel(const __half* __restrict__ h,
                                                   const int* __restrict__ off,
                                                   const int* __restrict__ csr,
                                                   const float* __restrict__ dinv,
                                                   const float* __restrict__ bias,
                                                   float* __restrict__ out, int N) {
  constexpr int NC = OUT_DIM;
  int node = blockIdx.x * 8 + (threadIdx.x >> 5);
  int hl = threadIdx.x & 31;
  if (node >= N) return;
  int c = hl * 2;
  float a0 = 0.f, a1 = 0.f;
  auto gather = [&](int sidx) {
    __half2 hv = *(const __half2*)(h + (size_t)sidx * NC + c);
    float2 f = __half22float2(hv);
    a0 += f.x;
    a1 += f.y;
  };
  gather(node);
  int e0 = off[node], e1 = off[node + 1];
  int e = e0;
  for (; e + 4 <= e1; e += 4) {
    int s0 = csr[e], s1 = csr[e + 1], s2 = csr[e + 2], s3 = csr[e + 3];
    gather(s0); gather(s1); gather(s2); gather(s3);
  }
  for (; e < e1; e++) gather(csr[e]);
  float di = dinv[node];
  out[(size_t)node * NC + c] = di * a0 + bias[c];
  out[(size_t)node * NC + c + 1] = di * a1 + bias[c + 1];
}

extern "C" void kernel_launch(void* const* d_in, const int* in_sizes, int n_in,
                              void* d_out, int out_size, void* d_ws, size_t ws_size,
                              hipStream_t stream) {
  const float* x  = (const float*)d_in[0];
  const int*   ei = (const int*)d_in[1];
  const float* W1 = (const float*)d_in[2];
  const float* b1 = (const float*)d_in[3];
  const float* W2 = (const float*)d_in[4];
  const float* b2 = (const float*)d_in[5];
  float* out = (float*)d_out;

  int N = in_sizes[0] / IN_DIM;
  int E = in_sizes[1] / 2;
  const int* src = ei;
  const int* dst = ei + E;
  int NB = (N + 127) >> BSHIFT;  // 782 for N=100000 (<= MAXNB)

  char* p = (char*)d_ws;
  auto alloc = [&](size_t bytes) {
    char* q = p;
    p += (bytes + 255) & ~(size_t)255;
    return q;
  };
  int*    bcnt  = (int*)alloc((size_t)NB * 4);
  int*    boff  = (int*)alloc((size_t)(NB + 1) * 4);
  int*    bcur  = (int*)alloc((size_t)NB * 4);
  int*    pairs = (int*)alloc((size_t)E * 4);   // packed (src<<7)|(dst&127)
  int*    csr   = (int*)alloc((size_t)E * 4);
  int*    off   = (int*)alloc((size_t)(N + 1) * 4);
  float*  dinv  = (float*)alloc((size_t)N * 4);
  __half* h1    = (__half*)alloc((size_t)N * HID_DIM * 2);  // reused as h2
  __half* z16   = (__half*)alloc((size_t)N * HID_DIM * 2);
  __half* Wt1   = (__half*)alloc((size_t)IN_DIM * HID_DIM * 2);
  __half* Wt2   = (__half*)alloc((size_t)HID_DIM * OUT_DIM * 2);
  __half* h2    = h1;
  (void)ws_size; (void)n_in; (void)out_size;

  hipMemsetAsync(bcnt, 0, (size_t)NB * 4, stream);

  bucket_hist<<<1024, 256, 0, stream>>>(dst, E, NB, bcnt, W1, W2, Wt1, Wt2);
  bucket_scan<<<1, 1024, 0, stream>>>(bcnt, NB, E, boff, bcur, off, N);
  int sblk = max(256, (E + STAGE_CAP - 1) / STAGE_CAP);  // 256 blocks, chunk 6250
  bucket_scatter<<<sblk, 256, 0, stream>>>(src, dst, E, NB, bcur, pairs);
  bucket_csr<<<NB, 256, 0, stream>>>(pairs, boff, N, csr, off, dinv);

  int gb = (N + 127) / 128;
  // layer 1: h1 rows pre-scaled by dinv (SCALE=true)
  mfma_gemm<IN_DIM, HID_DIM, float, true><<<gb, 256, 0, stream>>>(x, Wt1, h1, N, dinv);
  agg1_kernel<<<(N + 3) / 4, 256, 0, stream>>>(h1, off, csr, dinv, b1, z16, N);

  // layer 2: z16 already carries the dinv row-scale
  mfma_gemm<HID_DIM, OUT_DIM, __half, false><<<gb, 256, 0, stream>>>(z16, Wt2, h2, N, nullptr);
  agg2_kernel<<<(N + 7) / 8, 256, 0, stream>>>(h2, off, csr, dinv, b2, out, N);
}

// Round 13
// 400.317 us; speedup vs baseline: 1.8832x; 1.0192x over previous
//
#include <hip/hip_runtime.h>
#include <hip/hip_fp16.h>

// GCN: out = Ahat*(relu(Ahat*(x@W1)+b1))@W2 + b2,  Ahat = D^-1/2 (A+I) D^-1/2
// N=100000, E=1600000, IN=256, HID=128, OUT=64, fp32 in/out.
// R19 = R17 resubmit #2 (rounds 11+12 died on container acquisition -- 5th
//   infra flake; failure is pre-compile [no hipcc output, unlike round 10's
//   real compile error], and source has no fault vector: aligned in-bounds
//   NT stores, 65KB LDS, uniform barriers, R15-identical launch configs).
// R17 = R16 with compile fix: __builtin_nontemporal_store rejects __half2*
//   (struct type) -> bit-cast the half2 to unsigned int for the NT store.
// R16 = R15 + two surgical changes (R15 measured 408us, top = scatter 67.5us
//   @ 9.6% occ, VALU 5.8% -> latency-bound on 10-deep LDS binary search):
//   1) bucket_scatter: stage_bk[] records bucket id per slot (16-bit LDS);
//      writeout chain depth 10 -> 2. Grid stays 256 (bcur atomic contention
//      scales with block count: R12's 782 blocks -> 83us).
//   2) agg1/agg2: non-temporal output stores (z16/out = 51MB of writes that
//      evicted the gather working set from L2).
//   Ledger: dinv-fold confirmed win (agg1 68.6 -> <=67, out of top-5).

#define IN_DIM 256
#define HID_DIM 128
#define OUT_DIM 64
#define BSHIFT 7
#define MAXNB 1024      // supports N <= 131072
#define STAGE_CAP 8192  // max edges staged per scatter block (32 KB LDS)

typedef _Float16 half8 __attribute__((ext_vector_type(8)));
typedef float floatx4 __attribute__((ext_vector_type(4)));
typedef float f2v __attribute__((ext_vector_type(2)));

// ---- build A: bucket histogram (LDS-privatized) + W^T fp16 conversion ----
__global__ __launch_bounds__(256) void bucket_hist(const int* __restrict__ dst, int E,
                                                   int NB, int* __restrict__ bcnt,
                                                   const float* __restrict__ W1,
                                                   const float* __restrict__ W2,
                                                   __half* __restrict__ Wt1,
                                                   __half* __restrict__ Wt2) {
  __shared__ int h[MAXNB];
  int t = threadIdx.x;
  int gid = blockIdx.x * 256 + t, gsz = gridDim.x * 256;
  // fold in the (tiny) weight transposes
  for (int i = gid; i < IN_DIM * HID_DIM; i += gsz) {
    int n = i / IN_DIM, k = i % IN_DIM;
    Wt1[i] = __float2half(W1[k * HID_DIM + n]);
  }
  for (int i = gid; i < HID_DIM * OUT_DIM; i += gsz) {
    int n = i / HID_DIM, k = i % HID_DIM;
    Wt2[i] = __float2half(W2[k * OUT_DIM + n]);
  }
  for (int i = t; i < MAXNB; i += 256) h[i] = 0;
  __syncthreads();
  for (int i = gid; i < E; i += gsz) atomicAdd(&h[dst[i] >> BSHIFT], 1);
  __syncthreads();
  for (int i = t; i < NB; i += 256) {
    int v = h[i];
    if (v) atomicAdd(&bcnt[i], v);
  }
}

// ---- build B: scan bucket counts; init global cursors; off[N]=E ----
__global__ __launch_bounds__(1024) void bucket_scan(const int* __restrict__ bcnt, int NB,
                                                    int E, int* __restrict__ boff,
                                                    int* __restrict__ bcur,
                                                    int* __restrict__ off, int N) {
  __shared__ int sh[1024];
  int t = threadIdx.x;
  int v = (t < NB) ? bcnt[t] : 0;
  sh[t] = v;
  __syncthreads();
  for (int s = 1; s < 1024; s <<= 1) {
    int a = (t >= s) ? sh[t - s] : 0;
    __syncthreads();
    sh[t] += a;
    __syncthreads();
  }
  if (t < NB) {
    int ex = sh[t] - v;
    boff[t] = ex;
    bcur[t] = ex;
  }
  if (t == 0) {
    boff[NB] = E;
    off[N] = E;
  }
}

// ---- build C: LDS-staged counting sort of each chunk, coalesced writeout ----
// pairs[g] = (src<<7)|(dst&127), bucket-contiguous.
__global__ __launch_bounds__(256) void bucket_scatter(const int* __restrict__ src,
                                                      const int* __restrict__ dst, int E,
                                                      int NB, int* __restrict__ bcur,
                                                      int* __restrict__ pairs) {
  __shared__ int hist[MAXNB];
  __shared__ int base_l[MAXNB];     // exclusive scan of hist (LDS slot base)
  __shared__ int base_g[MAXNB];     // this block's run base in global pairs[]
  __shared__ int cur[MAXNB];
  __shared__ int sm[256];
  __shared__ int stage[STAGE_CAP];
  __shared__ unsigned short stage_bk[STAGE_CAP];  // bucket id per slot
  int t = threadIdx.x;
  int chunk = (E + gridDim.x - 1) / gridDim.x;
  int s0 = blockIdx.x * chunk, s1 = min(E, s0 + chunk);
  int cnt = s1 - s0;  // <= STAGE_CAP by launch config

  for (int i = t; i < MAXNB; i += 256) hist[i] = 0;
  __syncthreads();
  for (int i = s0 + t; i < s1; i += 256) atomicAdd(&hist[dst[i] >> BSHIFT], 1);
  __syncthreads();
  // scan 1024 hist entries with 256 threads (4 each)
  {
    int i0 = t * 4;
    int v0 = hist[i0], v1 = hist[i0 + 1], v2 = hist[i0 + 2], v3 = hist[i0 + 3];
    int s = v0 + v1 + v2 + v3;
    sm[t] = s;
    __syncthreads();
    for (int st = 1; st < 256; st <<= 1) {
      int a = (t >= st) ? sm[t - st] : 0;
      __syncthreads();
      sm[t] += a;
      __syncthreads();
    }
    int ex = sm[t] - s;
    base_l[i0] = ex;
    base_l[i0 + 1] = ex + v0;
    base_l[i0 + 2] = ex + v0 + v1;
    base_l[i0 + 3] = ex + v0 + v1 + v2;
    cur[i0] = ex;
    cur[i0 + 1] = ex + v0;
    cur[i0 + 2] = ex + v0 + v1;
    cur[i0 + 3] = ex + v0 + v1 + v2;
    if (v0) base_g[i0] = atomicAdd(&bcur[i0], v0);
    if (v1) base_g[i0 + 1] = atomicAdd(&bcur[i0 + 1], v1);
    if (v2) base_g[i0 + 2] = atomicAdd(&bcur[i0 + 2], v2);
    if (v3) base_g[i0 + 3] = atomicAdd(&bcur[i0 + 3], v3);
  }
  __syncthreads();
  // rank-scatter into LDS stage (packed payload + bucket id)
  for (int i = s0 + t; i < s1; i += 256) {
    int d = dst[i];
    int bk = d >> BSHIFT;
    int r = atomicAdd(&cur[bk], 1);
    stage[r] = (src[i] << BSHIFT) | (d & ((1 << BSHIFT) - 1));
    stage_bk[r] = (unsigned short)bk;
  }
  __syncthreads();
  // coalesced writeout: slot j -> bucket via stage_bk (2-deep chain, no search)
  for (int j = t; j < cnt; j += 256) {
    int bk = stage_bk[j];
    pairs[base_g[bk] + (j - base_l[bk])] = stage[j];
  }
}

// ---- build D: per-bucket counting sort -> csr/off/dinv ----
__global__ __launch_bounds__(256) void bucket_csr(const int* __restrict__ pairs,
                                                  const int* __restrict__ boff, int N,
                                                  int* __restrict__ csr,
                                                  int* __restrict__ off,
                                                  float* __restrict__ dinv) {
  int b = blockIdx.x;
  int t = threadIdx.x;
  int n0 = b << BSHIFT;
  int cnt = min(128, N - n0);
  __shared__ int ldeg[128], sh[128], lcur[128];
  if (t < 128) ldeg[t] = 0;
  __syncthreads();
  int e0 = boff[b], e1 = boff[b + 1];
  for (int e = e0 + t; e < e1; e += 256) atomicAdd(&ldeg[pairs[e] & 127], 1);
  __syncthreads();
  int v = (t < 128) ? ldeg[t] : 0;
  if (t < 128) sh[t] = v;
  __syncthreads();
  for (int s = 1; s < 128; s <<= 1) {
    int a = (t < 128 && t >= s) ? sh[t - s] : 0;
    __syncthreads();
    if (t < 128) sh[t] += a;
    __syncthreads();
  }
  if (t < cnt) {
    int ex = sh[t] - v;
    off[n0 + t] = e0 + ex;
    dinv[n0 + t] = 1.0f / sqrtf((float)(v + 1));
    lcur[t] = ex;
  }
  __syncthreads();
  for (int e = e0 + t; e < e1; e += 256) {
    int pk = pairs[e];
    int r = atomicAdd(&lcur[pk & 127], 1);
    csr[e0 + r] = pk >> BSHIFT;
  }
}

// C[M x NC](fp16) = A[M x K] @ W[K x NC] via v_mfma_f32_16x16x32_f16.
// SCALE: multiply output row by rowscale[row] (dinv fold for layer 1).
template <int K, int NC, typename AT, bool SCALE>
__global__ __launch_bounds__(256) void mfma_gemm(const AT* __restrict__ A,
                                                 const __half* __restrict__ Wt,
                                                 __half* __restrict__ C, int M,
                                                 const float* __restrict__ rowscale) {
  constexpr int BK = 32;
  constexpr int STR = BK + 8;  // padded LDS row stride (halves) -> 2-way max
  constexpr int CT = NC / 16;
  __shared__ _Float16 As[128 * STR];
  __shared__ _Float16 Ws[NC * STR];
  int row0 = blockIdx.x * 128;
  int t = threadIdx.x;
  int wave = t >> 6, lane = t & 63, quad = lane >> 4, lr = lane & 15;
  floatx4 acc[2][CT] = {};
  int arow = t >> 1, ako = (t & 1) * 16;
  int grow = row0 + arow;

  for (int k0 = 0; k0 < K; k0 += BK) {
    {
      half8 h0 = {}, h1 = {};
      if (grow < M) {
        if constexpr (sizeof(AT) == 4) {
          const float4* ap = (const float4*)(A + (size_t)grow * K + k0 + ako);
          float4 v0 = ap[0], v1 = ap[1], v2 = ap[2], v3 = ap[3];
          h0[0] = (_Float16)v0.x; h0[1] = (_Float16)v0.y;
          h0[2] = (_Float16)v0.z; h0[3] = (_Float16)v0.w;
          h0[4] = (_Float16)v1.x; h0[5] = (_Float16)v1.y;
          h0[6] = (_Float16)v1.z; h0[7] = (_Float16)v1.w;
          h1[0] = (_Float16)v2.x; h1[1] = (_Float16)v2.y;
          h1[2] = (_Float16)v2.z; h1[3] = (_Float16)v2.w;
          h1[4] = (_Float16)v3.x; h1[5] = (_Float16)v3.y;
          h1[6] = (_Float16)v3.z; h1[7] = (_Float16)v3.w;
        } else {
          const half8* ap = (const half8*)(A + (size_t)grow * K + k0 + ako);
          h0 = ap[0];
          h1 = ap[1];
        }
      }
      *(half8*)&As[arow * STR + ako] = h0;
      *(half8*)&As[arow * STR + ako + 8] = h1;
    }
    if constexpr (NC == 128) {
      int r = t >> 1, ko = (t & 1) * 16;
      const half8* wp = (const half8*)(Wt + (size_t)r * K + k0 + ko);
      *(half8*)&Ws[r * STR + ko] = wp[0];
      *(half8*)&Ws[r * STR + ko + 8] = wp[1];
    } else {  // NC == 64
      int r = t >> 2, ko = (t & 3) * 8;
      *(half8*)&Ws[r * STR + ko] = *(const half8*)(Wt + (size_t)r * K + k0 + ko);
    }
    __syncthreads();
    {
      int a_off = (wave * 32 + lr) * STR + quad * 8;
      half8 a0 = *(const half8*)&As[a_off];
      half8 a1 = *(const half8*)&As[a_off + 16 * STR];
      int b_off = lr * STR + quad * 8;
#pragma unroll
      for (int ct = 0; ct < CT; ct++) {
        half8 bfr = *(const half8*)&Ws[b_off + ct * 16 * STR];
        acc[0][ct] = __builtin_amdgcn_mfma_f32_16x16x32_f16(a0, bfr, acc[0][ct], 0, 0, 0);
        acc[1][ct] = __builtin_amdgcn_mfma_f32_16x16x32_f16(a1, bfr, acc[1][ct], 0, 0, 0);
      }
    }
    __syncthreads();
  }
#pragma unroll
  for (int rt = 0; rt < 2; rt++) {
    int rbase = row0 + wave * 32 + rt * 16 + quad * 4;
#pragma unroll
    for (int i = 0; i < 4; i++) {
      int row = rbase + i;
      if (row < M) {
        float sc = 1.f;
        if constexpr (SCALE) sc = rowscale[row];
#pragma unroll
        for (int ct = 0; ct < CT; ct++) {
          int col = ct * 16 + lr;
          C[(size_t)row * NC + col] = __float2half(acc[rt][ct][i] * sc);
        }
      }
    }
  }
}

// agg layer 1: one wave per node, NC=128, lane covers 2 cols (__half2). x8
// unroll. h rows pre-scaled by dinv (gemm1 epilogue) -> NO per-edge dinv
// loads. Output stores di*relu(...) so layer 2 inherits the row scale.
// z16 stores are NON-TEMPORAL (write-around; stored as u32 bits --
// __builtin_nontemporal_store rejects the __half2 struct type).
__global__ __launch_bounds__(256) void agg1_kernel(const __half* __restrict__ h,
                                                   const int* __restrict__ off,
                                                   const int* __restrict__ csr,
                                                   const float* __restrict__ dinv,
                                                   const float* __restrict__ bias,
                                                   __half* __restrict__ out, int N) {
  constexpr int NC = HID_DIM;
  int node = blockIdx.x * 4 + (threadIdx.x >> 6);
  int lane = threadIdx.x & 63;
  if (node >= N) return;
  int c = lane * 2;
  float a0 = 0.f, a1 = 0.f;
  auto gather = [&](int sidx) {
    __half2 hv = *(const __half2*)(h + (size_t)sidx * NC + c);
    float2 f = __half22float2(hv);
    a0 += f.x;
    a1 += f.y;
  };
  gather(node);  // self-loop (row already carries dinv[node])
  int e0 = off[node], e1 = off[node + 1];
  int e = e0;
  for (; e + 8 <= e1; e += 8) {
    int s0 = csr[e], s1 = csr[e + 1], s2 = csr[e + 2], s3 = csr[e + 3];
    int s4 = csr[e + 4], s5 = csr[e + 5], s6 = csr[e + 6], s7 = csr[e + 7];
    gather(s0); gather(s1); gather(s2); gather(s3);
    gather(s4); gather(s5); gather(s6); gather(s7);
  }
  for (; e + 4 <= e1; e += 4) {
    int s0 = csr[e], s1 = csr[e + 1], s2 = csr[e + 2], s3 = csr[e + 3];
    gather(s0); gather(s1); gather(s2); gather(s3);
  }
  for (; e < e1; e++) gather(csr[e]);
  float di = dinv[node];
  float r0 = fmaxf(di * a0 + bias[c], 0.f) * di;      // trailing *di = L2 fold
  float r1 = fmaxf(di * a1 + bias[c + 1], 0.f) * di;
  __half2 hv = __floats2half2_rn(r0, r1);
  unsigned int bits;
  __builtin_memcpy(&bits, &hv, 4);
  __builtin_nontemporal_store(bits, (unsigned int*)(out + (size_t)node * NC + c));
}

// agg layer 2: NC=64 -> half-wave per node (32 lanes x __half2). x4 unroll.
// Rows pre-scaled via z16 fold -> no per-edge dinv loads. NT output stores.
__global__ __launch_bounds__(256) void agg2_kernel(const __half* __restrict__ h,
                                                   const int* __restrict__ off,
                                                   const int* __restrict__ csr,
                                                   const float* __restrict__ dinv,
                                                   const float* __restrict__ bias,
                                                   float* __restrict__ out, int N) {
  constexpr int NC = OUT_DIM;
  int node = blockIdx.x * 8 + (threadIdx.x >> 5);
  int hl = threadIdx.x & 31;
  if (node >= N) return;
  int c = hl * 2;
  float a0 = 0.f, a1 = 0.f;
  auto gather = [&](int sidx) {
    __half2 hv = *(const __half2*)(h + (size_t)sidx * NC + c);
    float2 f = __half22float2(hv);
    a0 += f.x;
    a1 += f.y;
  };
  gather(node);
  int e0 = off[node], e1 = off[node + 1];
  int e = e0;
  for (; e + 4 <= e1; e += 4) {
    int s0 = csr[e], s1 = csr[e + 1], s2 = csr[e + 2], s3 = csr[e + 3];
    gather(s0); gather(s1); gather(s2); gather(s3);
  }
  for (; e < e1; e++) gather(csr[e]);
  float di = dinv[node];
  f2v o;
  o[0] = di * a0 + bias[c];
  o[1] = di * a1 + bias[c + 1];
  __builtin_nontemporal_store(o, (f2v*)(out + (size_t)node * NC + c));
}

extern "C" void kernel_launch(void* const* d_in, const int* in_sizes, int n_in,
                              void* d_out, int out_size, void* d_ws, size_t ws_size,
                              hipStream_t stream) {
  const float* x  = (const float*)d_in[0];
  const int*   ei = (const int*)d_in[1];
  const float* W1 = (const float*)d_in[2];
  const float* b1 = (const float*)d_in[3];
  const float* W2 = (const float*)d_in[4];
  const float* b2 = (const float*)d_in[5];
  float* out = (float*)d_out;

  int N = in_sizes[0] / IN_DIM;
  int E = in_sizes[1] / 2;
  const int* src = ei;
  const int* dst = ei + E;
  int NB = (N + 127) >> BSHIFT;  // 782 for N=100000 (<= MAXNB)

  char* p = (char*)d_ws;
  auto alloc = [&](size_t bytes) {
    char* q = p;
    p += (bytes + 255) & ~(size_t)255;
    return q;
  };
  int*    bcnt  = (int*)alloc((size_t)NB * 4);
  int*    boff  = (int*)alloc((size_t)(NB + 1) * 4);
  int*    bcur  = (int*)alloc((size_t)NB * 4);
  int*    pairs = (int*)alloc((size_t)E * 4);   // packed (src<<7)|(dst&127)
  int*    csr   = (int*)alloc((size_t)E * 4);
  int*    off   = (int*)alloc((size_t)(N + 1) * 4);
  float*  dinv  = (float*)alloc((size_t)N * 4);
  __half* h1    = (__half*)alloc((size_t)N * HID_DIM * 2);  // reused as h2
  __half* z16   = (__half*)alloc((size_t)N * HID_DIM * 2);
  __half* Wt1   = (__half*)alloc((size_t)IN_DIM * HID_DIM * 2);
  __half* Wt2   = (__half*)alloc((size_t)HID_DIM * OUT_DIM * 2);
  __half* h2    = h1;
  (void)ws_size; (void)n_in; (void)out_size;

  hipMemsetAsync(bcnt, 0, (size_t)NB * 4, stream);

  bucket_hist<<<1024, 256, 0, stream>>>(dst, E, NB, bcnt, W1, W2, Wt1, Wt2);
  bucket_scan<<<1, 1024, 0, stream>>>(bcnt, NB, E, boff, bcur, off, N);
  int sblk = max(256, (E + STAGE_CAP - 1) / STAGE_CAP);  // 256 blocks, chunk 6250
  bucket_scatter<<<sblk, 256, 0, stream>>>(src, dst, E, NB, bcur, pairs);
  bucket_csr<<<NB, 256, 0, stream>>>(pairs, boff, N, csr, off, dinv);

  int gb = (N + 127) / 128;
  // layer 1: h1 rows pre-scaled by dinv (SCALE=true)
  mfma_gemm<IN_DIM, HID_DIM, float, true><<<gb, 256, 0, stream>>>(x, Wt1, h1, N, dinv);
  agg1_kernel<<<(N + 3) / 4, 256, 0, stream>>>(h1, off, csr, dinv, b1, z16, N);

  // layer 2: z16 already carries the dinv row-scale
  mfma_gemm<HID_DIM, OUT_DIM, __half, false><<<gb, 256, 0, stream>>>(z16, Wt2, h2, N, nullptr);
  agg2_kernel<<<(N + 7) / 8, 256, 0, stream>>>(h2, off, csr, dinv, b2, out, N);
}